// Round 9
// baseline (728.449 us; speedup 1.0000x reference)
//
#include <hip/hip_runtime.h>
#include <hip/hip_bf16.h>

typedef __bf16 bf16;
typedef __bf16 bf16x8 __attribute__((ext_vector_type(8)));
typedef float f32x4 __attribute__((ext_vector_type(4)));
typedef unsigned char u8;
typedef unsigned int u32;
typedef unsigned short u16;
typedef u16 ushort8 __attribute__((ext_vector_type(8)));

#define B_ 4
#define T_ 1024
#define NX_ 1024
#define NH_ 16
#define HD_ 64

__device__ __forceinline__ void gld16(const void* g, void* l) {
  __builtin_amdgcn_global_load_lds((const __attribute__((address_space(1))) void*)g,
                                   (__attribute__((address_space(3))) void*)l, 16, 0, 0);
}

// ---------- prep: contiguous fp32 -> bf16 ----------
__global__ __launch_bounds__(256) void k_cvt(const float* __restrict__ in, bf16* __restrict__ out, int n) {
  int i = (blockIdx.x * 256 + threadIdx.x) * 4;
  if (i + 3 < n) {
    float4 v = *(const float4*)(in + i);
    out[i] = (bf16)v.x; out[i + 1] = (bf16)v.y; out[i + 2] = (bf16)v.z; out[i + 3] = (bf16)v.w;
  }
}

// ---------- prep: (K,N) f32 -> (N,K) bf16 transpose ----------
__global__ __launch_bounds__(256) void k_transpose(const float* __restrict__ in, bf16* __restrict__ out, int K, int N) {
  __shared__ float tile[64][65];
  int n0 = blockIdx.x * 64, k0 = blockIdx.y * 64;
  for (int i = threadIdx.x; i < 4096; i += 256) {
    int r = i >> 6, c = i & 63;
    tile[r][c] = in[(size_t)(k0 + r) * N + n0 + c];
  }
  __syncthreads();
  for (int i = threadIdx.x; i < 4096; i += 256) {
    int r = i >> 6, c = i & 63;
    out[(size_t)(n0 + r) * K + k0 + c] = (bf16)tile[c][r];
  }
}

// ---------- pack ids into per-(b,tt,st) 1KB tiles: [2][16t][32s] u8 (R then I) ----------
__global__ __launch_bounds__(256) void k_pack(const int* __restrict__ rel, const int* __restrict__ rel_ids,
                                              u8* __restrict__ rib) {
  int tt = blockIdx.x, b = blockIdx.y;
  int tid = threadIdx.x;
  int half = tid >> 7;                       // 0: rel, 1: rel_ids
  int t = (tid & 127) >> 3, g = tid & 7;     // row 0..15, 16B group 0..7
  const int* srcrow = (half ? rel_ids : rel + (size_t)b * T_ * T_) + (size_t)(tt * 16 + t) * T_ + g * 4;
  u8* dst = rib + ((size_t)(b * 64 + tt) * 32) * 1024 + half * 512 + t * 32 + g * 4;
  for (int st = 0; st < 32; ++st) {
    int4 v = *(const int4*)(srcrow + st * 32);
    uchar4 o = {(u8)v.x, (u8)v.y, (u8)v.z, (u8)v.w};
    *(uchar4*)(dst + (size_t)st * 1024) = o;
  }
}

// ---------- 128x128 bf16 MFMA GEMM, BK=32, double-buffered global_load_lds ----------
// EPI 0 epilogue writes q rows + K/V as per-(bh,st) contiguous LDS-swizzled 4KB tiles.
template <int EPI>
__global__ __launch_bounds__(256) void k_gemm(
    const bf16* __restrict__ A, const bf16* __restrict__ BT, const float* __restrict__ bias,
    float* __restrict__ outF, bf16* __restrict__ qg, bf16* __restrict__ kg, bf16* __restrict__ vtg,
    int M, int N, int K) {
  __shared__ __align__(16) bf16 Ab[2][128 * 32];
  __shared__ __align__(16) bf16 Bb[2][128 * 32];
  int tid = threadIdx.x, lane = tid & 63, w = tid >> 6;
  int wm = w >> 1, wn = w & 1;
  int m0 = blockIdx.y * 128, n0 = blockIdx.x * 128;
  int sl = lane >> 4, lr = lane & 15;
  f32x4 acc[4][4] = {};
  int NKt = K >> 5;

  auto stage = [&](int kt, int bidx) {
    const bf16* Ag = A + (size_t)m0 * K + kt * 32;
    const bf16* Bg = BT + (size_t)n0 * K + kt * 32;
#pragma unroll
    for (int j = 0; j < 2; ++j) {
      int c = w * 128 + j * 64 + lane;
      int row = c >> 2, slot = c & 3;
      int ss = slot ^ ((row >> 1) & 3);
      gld16(Ag + (size_t)row * K + ss * 8, &Ab[bidx][(w * 128 + j * 64) * 8]);
      gld16(Bg + (size_t)row * K + ss * 8, &Bb[bidx][(w * 128 + j * 64) * 8]);
    }
  };
  stage(0, 0);
  for (int kt = 0; kt < NKt; ++kt) {
    int bidx = kt & 1;
    __syncthreads();
    if (kt + 1 < NKt) stage(kt + 1, bidx ^ 1);
    bf16x8 af[4], bfv[4];
#pragma unroll
    for (int mi = 0; mi < 4; ++mi) {
      int row = wm * 64 + mi * 16 + lr;
      af[mi] = *(const bf16x8*)&Ab[bidx][row * 32 + ((sl ^ ((row >> 1) & 3)) * 8)];
    }
#pragma unroll
    for (int ni = 0; ni < 4; ++ni) {
      int row = wn * 64 + ni * 16 + lr;
      bfv[ni] = *(const bf16x8*)&Bb[bidx][row * 32 + ((sl ^ ((row >> 1) & 3)) * 8)];
    }
#pragma unroll
    for (int mi = 0; mi < 4; ++mi)
#pragma unroll
      for (int ni = 0; ni < 4; ++ni)
        acc[mi][ni] = __builtin_amdgcn_mfma_f32_16x16x32_bf16(af[mi], bfv[ni], acc[mi][ni], 0, 0, 0);
  }
#pragma unroll
  for (int ni = 0; ni < 4; ++ni) {
    int n = n0 + wn * 64 + ni * 16 + lr;
    float bv = bias[n];
#pragma unroll
    for (int mi = 0; mi < 4; ++mi) {
      int mb = m0 + wm * 64 + mi * 16 + sl * 4;
#pragma unroll
      for (int r = 0; r < 4; ++r) {
        float v = acc[mi][ni][r] + bv;
        int m = mb + r;
        if (EPI == 0) {
          int region = n >> 10, hh = (n & 1023) >> 6, d = n & 63;
          int bb = m >> 10, t = m & 1023;
          int bh = bb * NH_ + hh;
          int st = t >> 5, s = t & 31;
          if (region == 0) {
            qg[((size_t)bh * T_ + t) * HD_ + d] = (bf16)v;
          } else if (region == 1) {
            // K tile [32s][64d], d-slot(8x8el) swizzled by s&7
            int dpos = (d & 7) | ((((d >> 3) ^ (s & 7)) & 7) << 3);
            kg[((size_t)(bh * 32 + st) * 32 + s) * 64 + dpos] = (bf16)v;
          } else {
            // V tile [64d][32s], s-slot(4x8el) swizzled by (d>>1)&3
            int spos = (s & 7) | ((((s >> 3) ^ ((d >> 1) & 3)) & 3) << 3);
            vtg[((size_t)(bh * 32 + st) * 64 + d) * 32 + spos] = (bf16)v;
          }
        } else {
          outF[(size_t)m * N + n] = v;
        }
      }
    }
  }
}

// ---------- wave-independent fused attention; staging = 9 contiguous 1KB bursts ----------
struct MainSm {
  bf16 KB[2][2048];   // K  [32s][64d], pre-swizzled tiles
  bf16 VB[2][2048];   // V^T[64d][32s], pre-swizzled tiles
  bf16 PB[512];       // P  [16t][32s], slot^=(t&3)
  u8 IDS[2][1024];    // [2][16t][32s]: R | I
  float prel[1024];   // [16t][64] buckets
  float tab[64];
};
struct EpiSm {
  float ob[2048];     // overlays KB: O^T readback [16][68]
  float rvb[2048];    // overlays VB: rel_values half
};
union SmU { MainSm m; EpiSm e; };

// V: 0 full; 1 stage-only pipelined; 2 stage-only serial; 3 compute-only; 4 full minus atomics
template <int V>
__device__ __forceinline__ void attn_body(
    const bf16* __restrict__ qg, const bf16* __restrict__ kg, const bf16* __restrict__ vtg,
    const u8* __restrict__ rib, const float* __restrict__ rel_weights,
    const float* __restrict__ rel_values, bf16* __restrict__ ret) {
  __shared__ __align__(16) SmU sm;

  int bx = blockIdx.x;
  int tt = 63 - (bx & 63);                // heavy strips first
  int h = (bx >> 6) & 15, b = bx >> 10;
  int bh = b * NH_ + h;
  int t0 = tt * 16;
  int lane = threadIdx.x;
  int lr = lane & 15, sl = lane >> 4;

  sm.m.tab[lane] = __expf(rel_weights[lane * NH_ + h]);
#pragma unroll
  for (int i = 0; i < 4; ++i) ((float4*)sm.m.prel)[lane + 64 * i] = float4{0.f, 0.f, 0.f, 0.f};

  const bf16* qrow = qg + ((size_t)bh * T_ + t0 + lr) * HD_;
  bf16x8 qf0 = *(const bf16x8*)(qrow + sl * 8);
  bf16x8 qf1 = *(const bf16x8*)(qrow + 32 + sl * 8);

  // per-lane contiguous-burst staging sources (lane*16B within each 1KB chunk)
  const bf16* ktiles = kg + (size_t)bh * 32 * 2048 + lane * 8;
  const bf16* vtiles = vtg + (size_t)bh * 32 * 2048 + lane * 8;
  const u8* itiles = rib + (size_t)(b * 64 + tt) * 32 * 1024 + lane * 16;

  auto stage = [&](int st, int bidx) {
    const bf16* kb = ktiles + (size_t)st * 2048;
    const bf16* vb = vtiles + (size_t)st * 2048;
#pragma unroll
    for (int g = 0; g < 4; ++g) gld16(kb + g * 512, &sm.m.KB[bidx][g * 512]);
#pragma unroll
    for (int g = 0; g < 4; ++g) gld16(vb + g * 512, &sm.m.VB[bidx][g * 512]);
    gld16(itiles + (size_t)st * 1024, &sm.m.IDS[bidx][0]);
  };

  f32x4 acc[4] = {};
  float lsum = 0.f;
  int n = (tt >> 1) + 1;

  if constexpr (V == 2) {
    for (int st = 0; st < n; ++st) {
      stage(st, st & 1);
      asm volatile("s_waitcnt vmcnt(0)" ::: "memory");
      __builtin_amdgcn_sched_barrier(0);
    }
    return;
  }

  stage(0, 0);
  if constexpr (V == 3) {
    stage(1, 1);
    asm volatile("s_waitcnt vmcnt(0)" ::: "memory");
  }
  for (int st = 0; st < n; ++st) {
    int cur = st & 1;
    int s0 = st * 32;
    asm volatile("s_waitcnt lgkmcnt(0)" ::: "memory");
    if constexpr (V != 3) {
      if (st + 1 < n) {
        stage(st + 1, cur ^ 1);
        asm volatile("s_waitcnt vmcnt(9)" ::: "memory");
      } else {
        asm volatile("s_waitcnt vmcnt(0)" ::: "memory");
      }
    }
    __builtin_amdgcn_sched_barrier(0);
    if constexpr (V == 1) continue;

    // S^T = K * Q
    f32x4 S[2] = {};
#pragma unroll
    for (int si = 0; si < 2; ++si) {
      int srow = si * 16 + lr;
#pragma unroll
      for (int dsi = 0; dsi < 2; ++dsi) {
        bf16x8 ka = *(const bf16x8*)&sm.m.KB[cur][srow * 64 + (((dsi * 4 + sl) ^ (lr & 7)) * 8)];
        S[si] = __builtin_amdgcn_mfma_f32_16x16x32_bf16(ka, dsi ? qf1 : qf0, S[si], 0, 0, 0);
      }
    }
    // exp(S/8)*tab[rel], mask, P write, bucket atomics
    int tglob = t0 + lr;
#pragma unroll
    for (int si = 0; si < 2; ++si) {
      int sbase = s0 + si * 16 + sl * 4;
      u32 rid = *(const u32*)&sm.m.IDS[cur][lr * 32 + si * 16 + sl * 4];
      u32 iid = *(const u32*)&sm.m.IDS[cur][512 + lr * 32 + si * 16 + sl * 4];
      u16 pb4[4];
#pragma unroll
      for (int r = 0; r < 4; ++r) {
        bool on = (sbase + r <= tglob);
        float e = on ? __expf(S[si][r] * 0.125f) * sm.m.tab[(rid >> (8 * r)) & 63] : 0.f;
        lsum += e;
        bf16 eb = (bf16)e;
        pb4[r] = *(u16*)&eb;
        if constexpr (V != 4)
          if (e != 0.f) atomicAdd(&sm.m.prel[lr * 64 + ((iid >> (8 * r)) & 63)], e);
      }
      int slot = (si * 2 + (sl >> 1)) ^ (lr & 3);
      *(uint2*)&sm.m.PB[lr * 32 + slot * 8 + (sl & 1) * 4] =
          uint2{(u32)pb4[0] | ((u32)pb4[1] << 16), (u32)pb4[2] | ((u32)pb4[3] << 16)};
    }
    // O^T += V^T * P^T
    bf16x8 pbf = *(const bf16x8*)&sm.m.PB[lr * 32 + ((sl ^ (lr & 3)) * 8)];
#pragma unroll
    for (int ni = 0; ni < 4; ++ni) {
      int d = ni * 16 + lr;
      bf16x8 va = *(const bf16x8*)&sm.m.VB[cur][d * 32 + ((sl ^ ((lr >> 1) & 3)) * 8)];
      acc[ni] = __builtin_amdgcn_mfma_f32_16x16x32_bf16(va, pbf, acc[ni], 0, 0, 0);
    }
  }

  if constexpr (V != 0) {
    asm volatile("" :: "v"(lsum));
#pragma unroll
    for (int ni = 0; ni < 4; ++ni)
#pragma unroll
      for (int r = 0; r < 4; ++r) asm volatile("" :: "v"(acc[ni][r]));
    return;
  }

  // ---- epilogue (wave-local) ----
  float v = lsum;
  v += __shfl_xor(v, 16);
  v += __shfl_xor(v, 32);
  float inv = 1.f / v;

  asm volatile("s_waitcnt lgkmcnt(0)" ::: "memory");
  __builtin_amdgcn_sched_barrier(0);
  float* ob = sm.e.ob;
#pragma unroll
  for (int ni = 0; ni < 4; ++ni)
#pragma unroll
    for (int r = 0; r < 4; ++r)
      ob[lr * 68 + ni * 16 + sl * 4 + r] = acc[ni][r];

  int th = lane >> 2, q = lane & 3;
  f32x4 o[4], racc[4] = {};
#pragma unroll
  for (int i = 0; i < 4; ++i)
    o[i] = *(const f32x4*)&ob[th * 68 + q * 16 + i * 4];
  float invt = __shfl(inv, th);

  float* rvb = sm.e.rvb;
#pragma unroll
  for (int p = 0; p < 2; ++p) {
    asm volatile("s_waitcnt lgkmcnt(0)" ::: "memory");
    __builtin_amdgcn_sched_barrier(0);
#pragma unroll
    for (int g = 0; g < 8; ++g)
      gld16(rel_values + p * 2048 + g * 256 + lane * 4, &rvb[g * 256]);
    asm volatile("s_waitcnt vmcnt(0)" ::: "memory");
    __builtin_amdgcn_sched_barrier(0);
    for (int rr = 0; rr < 32; ++rr) {
      float pv = sm.m.prel[th * 64 + p * 32 + rr];
#pragma unroll
      for (int i = 0; i < 4; ++i)
        racc[i] += pv * *(const f32x4*)&rvb[rr * 64 + q * 16 + i * 4];
    }
  }

  u16 outv[16];
#pragma unroll
  for (int i = 0; i < 4; ++i)
#pragma unroll
    for (int j = 0; j < 4; ++j) {
      bf16 ob16 = (bf16)((o[i][j] + racc[i][j]) * invt);
      outv[i * 4 + j] = *(u16*)&ob16;
    }
  bf16* rp = ret + ((size_t)(b * T_ + t0 + th) * NX_ + h * HD_ + q * 16);
  *(ushort8*)rp = *(ushort8*)&outv[0];
  *(ushort8*)(rp + 8) = *(ushort8*)&outv[8];
}

#define ATTN_ARGS const bf16* qg, const bf16* kg, const bf16* vtg, const u8* rib, \
                  const float* rw, const float* rv, bf16* ret
__global__ __launch_bounds__(64) void k_attn(ATTN_ARGS)    { attn_body<0>(qg, kg, vtg, rib, rw, rv, ret); }
__global__ __launch_bounds__(64) void ka_pstage(ATTN_ARGS) { attn_body<1>(qg, kg, vtg, rib, rw, rv, ret); }
__global__ __launch_bounds__(64) void ka_sstage(ATTN_ARGS) { attn_body<2>(qg, kg, vtg, rib, rw, rv, ret); }
__global__ __launch_bounds__(64) void ka_comp(ATTN_ARGS)   { attn_body<3>(qg, kg, vtg, rib, rw, rv, ret); }
__global__ __launch_bounds__(64) void ka_noatom(ATTN_ARGS) { attn_body<4>(qg, kg, vtg, rib, rw, rv, ret); }

extern "C" void kernel_launch(void* const* d_in, const int* in_sizes, int n_in,
                              void* d_out, int out_size, void* d_ws, size_t ws_size,
                              hipStream_t stream) {
  const float* x = (const float*)d_in[0];
  const int* rel = (const int*)d_in[1];
  const float* w_attn = (const float*)d_in[2];
  const float* b_attn = (const float*)d_in[3];
  const float* w_proj = (const float*)d_in[4];
  const float* b_proj = (const float*)d_in[5];
  const float* rel_weights = (const float*)d_in[6];
  const float* rel_values = (const float*)d_in[7];
  const int* rel_ids = (const int*)d_in[8];
  float* out = (float*)d_out;

  char* ws = (char*)d_ws;
  bf16* xb  = (bf16*)(ws);                    //  8 MB: x as bf16 (consumed by gemm<0>)
  bf16* wTa = (bf16*)(ws + 8388608);          //  6 MB: w_attn^T
  bf16* wTp = (bf16*)(ws + 14680064);         //  2 MB: w_proj^T
  bf16* qg  = (bf16*)(ws + 16777216);         //  8 MB: q rows (bh,t,d)
  bf16* kg  = (bf16*)(ws + 25165824);         //  8 MB: K tiles (bh,st,32s,64d) swizzled
  bf16* vtg = (bf16*)(ws + 33554432);         //  8 MB: V tiles (bh,st,64d,32s) swizzled
  bf16* ret = (bf16*)(ws + 41943040);         //  8 MB: attn out (b,t,nx)
  u8* rib   = (u8*)(ws);                      //  8 MB: id tiles (b,tt,st,2,16,32), overlays dead xb

  k_cvt<<<4096, 256, 0, stream>>>(x, xb, 4194304);
  k_transpose<<<dim3(48, 16), 256, 0, stream>>>(w_attn, wTa, 1024, 3072);
  k_transpose<<<dim3(16, 16), 256, 0, stream>>>(w_proj, wTp, 1024, 1024);
  k_gemm<0><<<dim3(24, 32), 256, 0, stream>>>(xb, wTa, b_attn, nullptr, qg, kg, vtg, 4096, 3072, 1024);
  k_pack<<<dim3(64, 4), 256, 0, stream>>>(rel, rel_ids, rib);
  k_attn<<<4096, 64, 0, stream>>>(qg, kg, vtg, rib, rel_weights, rel_values, ret);
  k_gemm<1><<<dim3(8, 32), 256, 0, stream>>>(ret, wTp, b_proj, out, nullptr, nullptr, nullptr, 4096, 1024, 1024);
  // ---- diagnostic probes (half grid, distinct names; dropped next round) ----
  ka_pstage<<<2048, 64, 0, stream>>>(qg, kg, vtg, rib, rel_weights, rel_values, ret);
  ka_sstage<<<2048, 64, 0, stream>>>(qg, kg, vtg, rib, rel_weights, rel_values, ret);
  ka_comp<<<2048, 64, 0, stream>>>(qg, kg, vtg, rib, rel_weights, rel_values, ret);
  ka_noatom<<<2048, 64, 0, stream>>>(qg, kg, vtg, rib, rel_weights, rel_values, ret);
}

// Round 11
// 373.320 us; speedup vs baseline: 1.9513x; 1.9513x over previous
//
#include <hip/hip_runtime.h>
#include <hip/hip_bf16.h>

typedef __bf16 bf16;
typedef __bf16 bf16x8 __attribute__((ext_vector_type(8)));
typedef float f32x4 __attribute__((ext_vector_type(4)));
typedef unsigned char u8;
typedef unsigned int u32;
typedef unsigned short u16;
typedef u16 ushort4v __attribute__((ext_vector_type(4)));
typedef u32 u32x4 __attribute__((ext_vector_type(4)));

#define B_ 4
#define T_ 1024
#define NX_ 1024
#define NH_ 16
#define HD_ 64

__device__ __forceinline__ void gld16(const void* g, void* l) {
  __builtin_amdgcn_global_load_lds((const __attribute__((address_space(1))) void*)g,
                                   (__attribute__((address_space(3))) void*)l, 16, 0, 0);
}

// ---------- prep: contiguous fp32 -> bf16 ----------
__global__ __launch_bounds__(256) void k_cvt(const float* __restrict__ in, bf16* __restrict__ out, int n) {
  int i = (blockIdx.x * 256 + threadIdx.x) * 4;
  if (i + 3 < n) {
    float4 v = *(const float4*)(in + i);
    out[i] = (bf16)v.x; out[i + 1] = (bf16)v.y; out[i + 2] = (bf16)v.z; out[i + 3] = (bf16)v.w;
  }
}

// ---------- prep: (K,N) f32 -> (N,K) bf16 transpose ----------
__global__ __launch_bounds__(256) void k_transpose(const float* __restrict__ in, bf16* __restrict__ out, int K, int N) {
  __shared__ float tile[64][65];
  int n0 = blockIdx.x * 64, k0 = blockIdx.y * 64;
  for (int i = threadIdx.x; i < 4096; i += 256) {
    int r = i >> 6, c = i & 63;
    tile[r][c] = in[(size_t)(k0 + r) * N + n0 + c];
  }
  __syncthreads();
  for (int i = threadIdx.x; i < 4096; i += 256) {
    int r = i >> 6, c = i & 63;
    out[(size_t)(n0 + r) * K + k0 + c] = (bf16)tile[c][r];
  }
}

// ---------- pack int32 ids -> u8 ([t][s] natural layout; rel 4MB then rel_ids 1MB) ----------
__global__ __launch_bounds__(256) void k_pack(const int* __restrict__ rel, const int* __restrict__ rel_ids,
                                              u8* __restrict__ dst8) {
  int i = (blockIdx.x * 256 + threadIdx.x) * 4;
  const int* src = (i < 4194304) ? (rel + i) : (rel_ids + (i - 4194304));
  int4 v = *(const int4*)src;
  uchar4 o = {(u8)v.x, (u8)v.y, (u8)v.z, (u8)v.w};
  *(uchar4*)(dst8 + i) = o;
}

// ---------- rel_values^T as bf16 (64d x 64rr) for epilogue MFMA ----------
__global__ __launch_bounds__(256) void k_rvt(const float* __restrict__ rel_values, bf16* __restrict__ rvT) {
  int d = threadIdx.x >> 2, seg = threadIdx.x & 3;
  for (int i = 0; i < 16; ++i) {
    int rr = seg * 16 + i;
    rvT[d * 64 + rr] = (bf16)rel_values[rr * 64 + d];
  }
}

// ---------- 128x128 bf16 MFMA GEMM, BK=32, double-buffered global_load_lds ----------
template <int EPI>
__global__ __launch_bounds__(256) void k_gemm(
    const bf16* __restrict__ A, const bf16* __restrict__ BT, const float* __restrict__ bias,
    float* __restrict__ outF, bf16* __restrict__ qg, bf16* __restrict__ kg, bf16* __restrict__ vtg,
    int M, int N, int K) {
  __shared__ __align__(16) bf16 Ab[2][128 * 32];
  __shared__ __align__(16) bf16 Bb[2][128 * 32];
  int tid = threadIdx.x, lane = tid & 63, w = tid >> 6;
  int wm = w >> 1, wn = w & 1;
  int m0 = blockIdx.y * 128, n0 = blockIdx.x * 128;
  int sl = lane >> 4, lr = lane & 15;
  f32x4 acc[4][4] = {};
  int NKt = K >> 5;

  auto stage = [&](int kt, int bidx) {
    const bf16* Ag = A + (size_t)m0 * K + kt * 32;
    const bf16* Bg = BT + (size_t)n0 * K + kt * 32;
#pragma unroll
    for (int j = 0; j < 2; ++j) {
      int c = w * 128 + j * 64 + lane;
      int row = c >> 2, slot = c & 3;
      int ss = slot ^ ((row >> 1) & 3);
      gld16(Ag + (size_t)row * K + ss * 8, &Ab[bidx][(w * 128 + j * 64) * 8]);
      gld16(Bg + (size_t)row * K + ss * 8, &Bb[bidx][(w * 128 + j * 64) * 8]);
    }
  };
  stage(0, 0);
  for (int kt = 0; kt < NKt; ++kt) {
    int bidx = kt & 1;
    __syncthreads();
    if (kt + 1 < NKt) stage(kt + 1, bidx ^ 1);
    bf16x8 af[4], bfv[4];
#pragma unroll
    for (int mi = 0; mi < 4; ++mi) {
      int row = wm * 64 + mi * 16 + lr;
      af[mi] = *(const bf16x8*)&Ab[bidx][row * 32 + ((sl ^ ((row >> 1) & 3)) * 8)];
    }
#pragma unroll
    for (int ni = 0; ni < 4; ++ni) {
      int row = wn * 64 + ni * 16 + lr;
      bfv[ni] = *(const bf16x8*)&Bb[bidx][row * 32 + ((sl ^ ((row >> 1) & 3)) * 8)];
    }
#pragma unroll
    for (int mi = 0; mi < 4; ++mi)
#pragma unroll
      for (int ni = 0; ni < 4; ++ni)
        acc[mi][ni] = __builtin_amdgcn_mfma_f32_16x16x32_bf16(af[mi], bfv[ni], acc[mi][ni], 0, 0, 0);
  }
#pragma unroll
  for (int ni = 0; ni < 4; ++ni) {
    int n = n0 + wn * 64 + ni * 16 + lr;
    float bv = bias[n];
#pragma unroll
    for (int mi = 0; mi < 4; ++mi) {
      int mb = m0 + wm * 64 + mi * 16 + sl * 4;
#pragma unroll
      for (int r = 0; r < 4; ++r) {
        float v = acc[mi][ni][r] + bv;
        int m = mb + r;
        if (EPI == 0) {
          int region = n >> 10, hh = (n & 1023) >> 6, d = n & 63;
          int bb = m >> 10, t = m & 1023;
          int bh = bb * NH_ + hh;
          if (region == 0)      qg[((size_t)bh * T_ + t) * HD_ + d] = (bf16)v;
          else if (region == 1) kg[((size_t)bh * T_ + t) * HD_ + d] = (bf16)v;
          else                  vtg[((size_t)bh * HD_ + d) * T_ + t] = (bf16)v;
        } else {
          outF[(size_t)m * N + n] = v;
        }
      }
    }
  }
}

// ---------- register-staged wave-independent fused attention ----------
// 1 wave per 16-row Q strip. No global_load_lds, no K/V LDS tiles. LDS = prel+tab (4.6KB).
// S^T = mfma(K,Q): lane(lr,sl): t=lr, s=si*16+sl*4+r.  O^T = mfma(V^T,P^T): t=lr, d=ni*16+sl*4+r.
struct KVregs {
  bf16x8 k00, k01, k10, k11;   // K frag [si][dsi]
  bf16x8 v0, v1, v2, v3;       // V^T frag [ni]
  u32 rid0, rid1, iid0, iid1;  // id dwords [si]
};

__global__ __launch_bounds__(64, 3) void k_attn(
    const bf16* __restrict__ qg, const bf16* __restrict__ kg, const bf16* __restrict__ vtg,
    const u8* __restrict__ rel8, const float* __restrict__ rel_weights,
    const u8* __restrict__ relid8, const bf16* __restrict__ rvT,
    bf16* __restrict__ ret) {
  __shared__ float prel[16 * 68];   // [16t][64+4pad] buckets
  __shared__ float tab[64];

  int bx = blockIdx.x;
  int tt = 63 - (bx & 63);          // heavy strips first
  int h = (bx >> 6) & 15, b = bx >> 10;
  int bh = b * NH_ + h;
  int t0 = tt * 16;
  int lane = threadIdx.x;
  int lr = lane & 15, sl = lane >> 4;

  tab[lane] = __expf(rel_weights[lane * NH_ + h]);
#pragma unroll
  for (int i = 0; i < 17; ++i) prel[i * 64 + lane] = 0.f;

  // Q B-frag: lane(lr,sl) holds Q[t=t0+lr][d = (qf0: sl*8..) (qf1: 32+sl*8..)]
  const bf16* qrow = qg + ((size_t)bh * T_ + t0 + lr) * HD_;
  bf16x8 qf0 = *(const bf16x8*)(qrow + sl * 8);
  bf16x8 qf1 = *(const bf16x8*)(qrow + 32 + sl * 8);

  // per-lane base pointers
  const bf16* klane = kg + ((size_t)bh * T_ + lr) * HD_ + sl * 8;
  const bf16* vlane = vtg + ((size_t)bh * HD_ + lr) * T_ + sl * 8;
  const u8* ridlane = rel8 + (size_t)b * T_ * T_ + (size_t)(t0 + lr) * T_ + sl * 4;
  const u8* iidlane = relid8 + (size_t)(t0 + lr) * T_ + sl * 4;

  auto loadKV = [&](int st, KVregs& o) {
    int s0 = st * 32;
    o.k00 = *(const bf16x8*)(klane + (size_t)(s0 + 0) * HD_);
    o.k01 = *(const bf16x8*)(klane + (size_t)(s0 + 0) * HD_ + 32);
    o.k10 = *(const bf16x8*)(klane + (size_t)(s0 + 16) * HD_);
    o.k11 = *(const bf16x8*)(klane + (size_t)(s0 + 16) * HD_ + 32);
    o.v0 = *(const bf16x8*)(vlane + (size_t)(0 * 16) * T_ + s0);
    o.v1 = *(const bf16x8*)(vlane + (size_t)(1 * 16) * T_ + s0);
    o.v2 = *(const bf16x8*)(vlane + (size_t)(2 * 16) * T_ + s0);
    o.v3 = *(const bf16x8*)(vlane + (size_t)(3 * 16) * T_ + s0);
    o.rid0 = *(const u32*)(ridlane + s0);
    o.rid1 = *(const u32*)(ridlane + s0 + 16);
    o.iid0 = *(const u32*)(iidlane + s0);
    o.iid1 = *(const u32*)(iidlane + s0 + 16);
  };

  f32x4 acc[4] = {};
  float lsum = 0.f;
  int tglob = t0 + lr;

  auto compute = [&](const KVregs& c, int st) {
    int s0 = st * 32;
    // S^T = K * Q  (2 si x 2 d-chunks)
    f32x4 S0 = {}, S1 = {};
    S0 = __builtin_amdgcn_mfma_f32_16x16x32_bf16(c.k00, qf0, S0, 0, 0, 0);
    S0 = __builtin_amdgcn_mfma_f32_16x16x32_bf16(c.k01, qf1, S0, 0, 0, 0);
    S1 = __builtin_amdgcn_mfma_f32_16x16x32_bf16(c.k10, qf0, S1, 0, 0, 0);
    S1 = __builtin_amdgcn_mfma_f32_16x16x32_bf16(c.k11, qf1, S1, 0, 0, 0);
    // softmax (unnormalized) + bucket atomics + pack P
    u32 a0, b0, a1, b1;
    {
      u16 pb[8];
#pragma unroll
      for (int si = 0; si < 2; ++si) {
        f32x4 S = si ? S1 : S0;
        u32 rid = si ? c.rid1 : c.rid0;
        u32 iid = si ? c.iid1 : c.iid0;
        int sbase = s0 + si * 16 + sl * 4;
#pragma unroll
        for (int r = 0; r < 4; ++r) {
          float e = (sbase + r <= tglob) ? __expf(S[r] * 0.125f) * tab[(rid >> (8 * r)) & 63] : 0.f;
          lsum += e;
          bf16 eb = (bf16)e;
          pb[si * 4 + r] = *(u16*)&eb;
          if (e != 0.f) atomicAdd(&prel[lr * 68 + ((iid >> (8 * r)) & 63)], e);
        }
      }
      a0 = (u32)pb[0] | ((u32)pb[1] << 16);
      b0 = (u32)pb[2] | ((u32)pb[3] << 16);
      a1 = (u32)pb[4] | ((u32)pb[5] << 16);
      b1 = (u32)pb[6] | ((u32)pb[7] << 16);
    }
    // redistribute P -> B-frag of PV via shuffles: lane needs P[lr][sl*8..+8]
    int srcA = lr + (((sl & 1) * 2) << 4);
    int srcB = srcA + 16;
    u32 taA0 = (u32)__shfl((int)a0, srcA), taA1 = (u32)__shfl((int)a1, srcA);
    u32 tbA0 = (u32)__shfl((int)b0, srcA), tbA1 = (u32)__shfl((int)b1, srcA);
    u32 taB0 = (u32)__shfl((int)a0, srcB), taB1 = (u32)__shfl((int)a1, srcB);
    u32 tbB0 = (u32)__shfl((int)b0, srcB), tbB1 = (u32)__shfl((int)b1, srcB);
    bool hi = (sl & 2) != 0;
    u32x4 wv;
    wv[0] = hi ? taA1 : taA0;
    wv[1] = hi ? tbA1 : tbA0;
    wv[2] = hi ? taB1 : taB0;
    wv[3] = hi ? tbB1 : tbB0;
    bf16x8 pfrag = *(bf16x8*)&wv;
    // O^T += V^T * P^T
    acc[0] = __builtin_amdgcn_mfma_f32_16x16x32_bf16(c.v0, pfrag, acc[0], 0, 0, 0);
    acc[1] = __builtin_amdgcn_mfma_f32_16x16x32_bf16(c.v1, pfrag, acc[1], 0, 0, 0);
    acc[2] = __builtin_amdgcn_mfma_f32_16x16x32_bf16(c.v2, pfrag, acc[2], 0, 0, 0);
    acc[3] = __builtin_amdgcn_mfma_f32_16x16x32_bf16(c.v3, pfrag, acc[3], 0, 0, 0);
  };

  int nst = (tt >> 1) + 1;
  KVregs ra, rb;
  loadKV(0, ra);
  for (int st = 0; st < nst; st += 2) {
    if (st + 1 < nst) loadKV(st + 1, rb);
    compute(ra, st);
    if (st + 1 < nst) {
      if (st + 2 < nst) loadKV(st + 2, ra);
      compute(rb, st + 1);
    }
  }

  // ---- epilogue ----
  float v = lsum;
  v += __shfl_xor(v, 16);
  v += __shfl_xor(v, 32);
  float inv = 1.f / v;                 // per-lane, t = lr (uniform across sl)

  // rel-values term via MFMA: acc[ni] += rvT_frag x prel^T_frag
  asm volatile("s_waitcnt lgkmcnt(0)" ::: "memory");
  __builtin_amdgcn_sched_barrier(0);
#pragma unroll
  for (int kc = 0; kc < 2; ++kc) {
    // B-frag: prel[t=lr][rr = kc*32 + sl*8 .. +8] as bf16
    f32x4 pA = *(const f32x4*)&prel[lr * 68 + kc * 32 + sl * 8];
    f32x4 pB = *(const f32x4*)&prel[lr * 68 + kc * 32 + sl * 8 + 4];
    u16 pb[8];
#pragma unroll
    for (int j = 0; j < 4; ++j) { bf16 x = (bf16)pA[j]; pb[j] = *(u16*)&x; }
#pragma unroll
    for (int j = 0; j < 4; ++j) { bf16 x = (bf16)pB[j]; pb[4 + j] = *(u16*)&x; }
    bf16x8 pfrag = *(bf16x8*)&pb[0];
#pragma unroll
    for (int ni = 0; ni < 4; ++ni) {
      bf16x8 af = *(const bf16x8*)(rvT + (size_t)(ni * 16 + lr) * 64 + kc * 32 + sl * 8);
      acc[ni] = __builtin_amdgcn_mfma_f32_16x16x32_bf16(af, pfrag, acc[ni], 0, 0, 0);
    }
  }

  // normalize + store: lane(lr,sl) owns t=t0+lr, d = ni*16 + sl*4 .. +4
  bf16* rp = ret + ((size_t)(b * T_ + t0 + lr)) * NX_ + h * HD_ + sl * 4;
#pragma unroll
  for (int ni = 0; ni < 4; ++ni) {
    ushort4v ov;
#pragma unroll
    for (int r = 0; r < 4; ++r) {
      bf16 x = (bf16)(acc[ni][r] * inv);
      ov[r] = *(u16*)&x;
    }
    *(ushort4v*)(rp + ni * 16) = ov;
  }
}

extern "C" void kernel_launch(void* const* d_in, const int* in_sizes, int n_in,
                              void* d_out, int out_size, void* d_ws, size_t ws_size,
                              hipStream_t stream) {
  const float* x = (const float*)d_in[0];
  const int* rel = (const int*)d_in[1];
  const float* w_attn = (const float*)d_in[2];
  const float* b_attn = (const float*)d_in[3];
  const float* w_proj = (const float*)d_in[4];
  const float* b_proj = (const float*)d_in[5];
  const float* rel_weights = (const float*)d_in[6];
  const float* rel_values = (const float*)d_in[7];
  const int* rel_ids = (const int*)d_in[8];
  float* out = (float*)d_out;

  char* ws = (char*)d_ws;
  bf16* xb  = (bf16*)(ws);                    //  8 MB: x as bf16 (consumed by gemm<0>)
  bf16* wTa = (bf16*)(ws + 8388608);          //  6 MB: w_attn^T
  bf16* wTp = (bf16*)(ws + 14680064);         //  2 MB: w_proj^T
  bf16* qg  = (bf16*)(ws + 16777216);         //  8 MB: q (bh,t,d)
  bf16* kg  = (bf16*)(ws + 25165824);         //  8 MB: k (bh,t,d)
  bf16* vtg = (bf16*)(ws + 33554432);         //  8 MB: v^T (bh,d,t)
  bf16* ret = (bf16*)(ws + 41943040);         //  8 MB: attn out (b,t,nx)
  // overlays on dead xb region (after gemm<0> consumed it):
  u8* rel8   = (u8*)(ws);                     //  4 MB: rel ids u8 [b][t][s]
  u8* relid8 = (u8*)(ws + 4194304);           //  1 MB: rel_ids u8 [t][s]
  bf16* rvT  = (bf16*)(ws + 5242880);         //  8 KB: rel_values^T bf16 (64d x 64rr)

  k_cvt<<<4096, 256, 0, stream>>>(x, xb, 4194304);
  k_transpose<<<dim3(48, 16), 256, 0, stream>>>(w_attn, wTa, 1024, 3072);
  k_transpose<<<dim3(16, 16), 256, 0, stream>>>(w_proj, wTp, 1024, 1024);
  k_gemm<0><<<dim3(24, 32), 256, 0, stream>>>(xb, wTa, b_attn, nullptr, qg, kg, vtg, 4096, 3072, 1024);
  k_pack<<<5120, 256, 0, stream>>>(rel, rel_ids, rel8);
  k_rvt<<<1, 256, 0, stream>>>(rel_values, rvT);
  k_attn<<<4096, 64, 0, stream>>>(qg, kg, vtg, rel8, rel_weights, relid8, rvT, ret);
  k_gemm<1><<<dim3(8, 32), 256, 0, stream>>>(ret, wTp, b_proj, out, nullptr, nullptr, nullptr, 4096, 1024, 1024);
}